// Round 1
// 776.977 us; speedup vs baseline: 1.1286x; 1.1286x over previous
//
#include <hip/hip_runtime.h>

typedef _Float16 f16x8 __attribute__((ext_vector_type(8)));
typedef _Float16 f16x4 __attribute__((ext_vector_type(4)));
typedef float f32x4 __attribute__((ext_vector_type(4)));

#define B_SZ 64
#define H_SZ 128
#define S_SZ 4096
#define D_SZ 512
#define PE_SZ 64
#define NCHUNK 4
#define CHUNK 1024
#define NT 32
#define NTILES 32
#define CSCALE 0.06011229381f  // (1/sqrt(576)) * log2(e)
#define DEFER_LOG2 4.0f        // defer-rescale threshold: P bounded by 2^4

#define STAGE_PITCH 516   // fp32 elems per row (512 + 4 pad), 2064 B
#define KBUF_PITCH 584    // f16 elems per row (576 + 8 pad)
#define VTB_PITCH 40      // f16 elems per row (32 + 8 pad)
#define PB_PITCH 40
#define OB_PITCH 520

#define KBUF_OFF 66048
#define VTB_OFF 103424
#define PB_OFF 144384
#define AL_OFF 154624     // alpha[128] f32
#define LL_OFF 155136     // l[128] f32
#define SMEM_BYTES 155648

// partial workspace layout
#define WSO_BYTES (64ull * 4 * 128 * 512 * 2)   // fp16 partial O = 32 MiB
#define WSM_OFF WSO_BYTES
#define WSL_OFF (WSO_BYTES + 64ull * 4 * 128 * 4)
#define WS_NEEDED (WSO_BYTES + 2ull * 64 * 4 * 128 * 4)

__device__ __forceinline__ void async_copy16(const float* g, float* l) {
  __builtin_amdgcn_global_load_lds(
      (const __attribute__((address_space(1))) void*)g,
      (__attribute__((address_space(3))) void*)l, 16, 0, 0);
}

__launch_bounds__(512, 2)
__global__ void mla_partial(const float* __restrict__ Q, const float* __restrict__ Qpe,
                            const float* __restrict__ KV, const float* __restrict__ Kpe,
                            _Float16* __restrict__ wsO, float* __restrict__ wsM,
                            float* __restrict__ wsL) {
  __shared__ __align__(16) char smem[SMEM_BYTES];
  float* stage   = (float*)smem;                   // [32][516] fp32 KV staging (DMA target)
  _Float16* kbuf = (_Float16*)(smem + KBUF_OFF);   // [32][584] f16 K rows (seq-major, 576 cols)
  _Float16* vtb  = (_Float16*)(smem + VTB_OFF);    // [512][40] f16 V transposed (dim-major)
  _Float16* pb   = (_Float16*)(smem + PB_OFF);     // [128][40] P rows = heads, cols = seq
  float* al_lds  = (float*)(smem + AL_OFF);        // per-head alpha, this tile
  float* l_lds   = (float*)(smem + LL_OFF);        // per-head l, epilogue

  const int tid  = threadIdx.x;
  const int lane = tid & 63;
  const int w    = tid >> 6;
  const int quad = lane >> 4;
  const int l15  = lane & 15;
  const int hg   = w & 3;    // PV head-group: heads hg*32 .. hg*32+31
  const int dh   = w >> 2;   // PV dim-half: dims dh*256 .. dh*256+255

  const int b  = blockIdx.x >> 2;
  const int c  = blockIdx.x & 3;
  const int s0 = c * CHUNK;

  // ---- Q fragments, persistent in registers: head = w*16 + l15 ----
  // Used as the B-operand of the transposed QK^T (same per-lane data as A-use).
  f16x8 qf[18];
  {
    const int h = w * 16 + l15;
    const float* qrow  = Q   + (size_t)(b * H_SZ + h) * D_SZ;
    const float* qprow = Qpe + (size_t)(b * H_SZ + h) * PE_SZ;
#pragma unroll
    for (int kk = 0; kk < 18; ++kk) {
      const float* src = (kk < 16) ? (qrow + kk * 32 + quad * 8)
                                   : (qprow + (kk - 16) * 32 + quad * 8);
      f32x4 a0 = *(const f32x4*)(src);
      f32x4 a1 = *(const f32x4*)(src + 4);
      f16x8 f;
      f[0] = (_Float16)a0[0]; f[1] = (_Float16)a0[1];
      f[2] = (_Float16)a0[2]; f[3] = (_Float16)a0[3];
      f[4] = (_Float16)a1[0]; f[5] = (_Float16)a1[1];
      f[6] = (_Float16)a1[2]; f[7] = (_Float16)a1[3];
      qf[kk] = f;
    }
  }

  // ---- DMA of one 32-row KV tile into fp32 staging + K_pe tile into regs ----
  f32x4 kpe_r;
  auto dma_tile = [&](int t, f32x4& kpe_out) {
    const int sg_base = b * S_SZ + s0 + t * NT;
#pragma unroll
    for (int rr = 0; rr < 4; ++rr) {
      const int row = w * 4 + rr;
      const float* gk = KV + (size_t)(sg_base + row) * D_SZ;
      float* l0 = stage + row * STAGE_PITCH;
      async_copy16(gk + lane * 4, l0 + lane * 4);
      async_copy16(gk + 256 + lane * 4, l0 + 256 + lane * 4);
    }
    kpe_out = *(const f32x4*)(Kpe + (size_t)sg_base * PE_SZ + tid * 4);
  };

  // ---- convert staged fp32 -> f16 seq-major K rows + f16 transposed V ----
  auto convert_tile = [&](f32x4 kpe_in) {
#pragma unroll
    for (int i = 0; i < 8; ++i) {
      int lin  = tid + 512 * i;        // 0..4095
      int row  = lin >> 7;
      int col4 = lin & 127;
      f32x4 v = *(const f32x4*)(stage + row * STAGE_PITCH + col4 * 4);
      f16x4 h;
      h[0] = (_Float16)v[0]; h[1] = (_Float16)v[1];
      h[2] = (_Float16)v[2]; h[3] = (_Float16)v[3];
      *(f16x4*)(kbuf + row * KBUF_PITCH + col4 * 4) = h;
    }
    {
      int row  = tid >> 4;
      int col4 = tid & 15;
      f16x4 h;
      h[0] = (_Float16)kpe_in[0]; h[1] = (_Float16)kpe_in[1];
      h[2] = (_Float16)kpe_in[2]; h[3] = (_Float16)kpe_in[3];
      *(f16x4*)(kbuf + row * KBUF_PITCH + 512 + col4 * 4) = h;
    }
#pragma unroll
    for (int g = 0; g < 2; ++g) {
      int lin   = tid + 512 * g;       // 0..1023
      int rg    = lin & 7;             // row group (4 seq rows)
      int cidx4 = lin >> 3;            // 0..127 (4 dims)
      f32x4 v0 = *(const f32x4*)(stage + (rg * 4 + 0) * STAGE_PITCH + cidx4 * 4);
      f32x4 v1 = *(const f32x4*)(stage + (rg * 4 + 1) * STAGE_PITCH + cidx4 * 4);
      f32x4 v2 = *(const f32x4*)(stage + (rg * 4 + 2) * STAGE_PITCH + cidx4 * 4);
      f32x4 v3 = *(const f32x4*)(stage + (rg * 4 + 3) * STAGE_PITCH + cidx4 * 4);
#pragma unroll
      for (int u = 0; u < 4; ++u) {
        f16x4 h;
        h[0] = (_Float16)v0[u]; h[1] = (_Float16)v1[u];
        h[2] = (_Float16)v2[u]; h[3] = (_Float16)v3[u];
        *(f16x4*)(vtb + (cidx4 * 4 + u) * VTB_PITCH + rg * 4) = h;
      }
    }
  };

  // ---- accumulators / softmax state ----
  // O[0..15]  = heads hg*32+ 0..15 (rows quad*4+i), dims dh*256 + nt*16 + l15
  // O[16..31] = heads hg*32+16..31
  f32x4 O[32];
#pragma unroll
  for (int i = 0; i < 32; ++i) O[i] = (f32x4){0.f, 0.f, 0.f, 0.f};
  float mr = -1e30f;   // running max for head w*16+l15 (quad-uniform)
  float lr = 0.f;      // running sum

  dma_tile(0, kpe_r);
  __syncthreads();   // drains DMA(0)
  convert_tile(kpe_r);
  __syncthreads();

  _Float16* pw = pb + w * 16 * PB_PITCH;

#pragma unroll 1
  for (int t = 0; t < NTILES; ++t) {
    f32x4 kpe_nxt;
    if (t < NTILES - 1) dma_tile(t + 1, kpe_nxt);  // async; drained at B2

    // ---- QK^T transposed: S^T tile 32 seq x 16 heads ----
    // A = K rows (m=seq=l15, k=dim), B = qf (n=head=l15, k=dim)
    f32x4 S0 = (f32x4){0.f, 0.f, 0.f, 0.f};
    f32x4 S1 = (f32x4){0.f, 0.f, 0.f, 0.f};
    const _Float16* kb0 = kbuf + l15 * KBUF_PITCH + quad * 8;
    const _Float16* kb1 = kbuf + (16 + l15) * KBUF_PITCH + quad * 8;
#pragma unroll
    for (int kk = 0; kk < 18; ++kk) {
      f16x8 b0 = *(const f16x8*)(kb0 + kk * 32);
      f16x8 b1 = *(const f16x8*)(kb1 + kk * 32);
      S0 = __builtin_amdgcn_mfma_f32_16x16x32_f16(b0, qf[kk], S0, 0, 0, 0);
      S1 = __builtin_amdgcn_mfma_f32_16x16x32_f16(b1, qf[kk], S1, 0, 0, 0);
    }
    // lane (quad,l15) holds S[seq=quad*4+i][head=l15] (S0) and seq+16 (S1)

    // ---- online softmax: in-lane over 8 seq + 2 cross-quad shuffles ----
    float mx = fmaxf(fmaxf(fmaxf(S0[0], S0[1]), fmaxf(S0[2], S0[3])),
                     fmaxf(fmaxf(S1[0], S1[1]), fmaxf(S1[2], S1[3])));
    mx = fmaxf(mx, __shfl_xor(mx, 16));
    mx = fmaxf(mx, __shfl_xor(mx, 32));
    const bool grow = (mx - mr) * CSCALE > DEFER_LOG2;   // defer-rescale (T13)
    const float mn = grow ? mx : mr;
    const float al = grow ? exp2f((mr - mn) * CSCALE) : 1.0f;
    float p0[4], p1[4], rs = 0.f;
#pragma unroll
    for (int i = 0; i < 4; ++i) {
      p0[i] = exp2f((S0[i] - mn) * CSCALE);
      p1[i] = exp2f((S1[i] - mn) * CSCALE);
      rs += p0[i] + p1[i];
    }
    rs += __shfl_xor(rs, 16);
    rs += __shfl_xor(rs, 32);
    lr = lr * al + rs;
    mr = mn;

    // ---- write P (f16, packed b64) + alpha; raw barrier (no vmcnt drain) ----
    f16x4 h0, h1;
#pragma unroll
    for (int i = 0; i < 4; ++i) { h0[i] = (_Float16)p0[i]; h1[i] = (_Float16)p1[i]; }
    *(f16x4*)(pw + l15 * PB_PITCH + quad * 4)      = h0;
    *(f16x4*)(pw + l15 * PB_PITCH + 16 + quad * 4) = h1;
    if (lane < 16) al_lds[w * 16 + lane] = al;
    // B1: P/alpha ready. lgkmcnt(0) only — DMA(t+1) stays in flight.
    asm volatile("s_waitcnt lgkmcnt(0)\n\ts_barrier" ::: "memory");
    __builtin_amdgcn_sched_barrier(0);

    // ---- PV dim-split: this wave: heads hg*32..+31, dims dh*256..+255 ----
    f32x4 av0 = *(const f32x4*)(al_lds + hg * 32 + quad * 4);
    f32x4 av1 = *(const f32x4*)(al_lds + hg * 32 + 16 + quad * 4);
    int stable = (av0[0] == 1.f) & (av0[1] == 1.f) & (av0[2] == 1.f) & (av0[3] == 1.f) &
                 (av1[0] == 1.f) & (av1[1] == 1.f) & (av1[2] == 1.f) & (av1[3] == 1.f);
    if (!__all(stable)) {
#pragma unroll
      for (int nt = 0; nt < 16; ++nt) { O[nt] *= av0; O[16 + nt] *= av1; }
    }
    f16x8 pa0 = *(const f16x8*)(pb + ((hg * 2 + 0) * 16 + l15) * PB_PITCH + quad * 8);
    f16x8 pa1 = *(const f16x8*)(pb + ((hg * 2 + 1) * 16 + l15) * PB_PITCH + quad * 8);
    const _Float16* vbase = vtb + (dh * 256 + l15) * VTB_PITCH + quad * 8;
#pragma unroll
    for (int nt = 0; nt < 16; ++nt) {
      f16x8 bv = *(const f16x8*)(vbase + nt * 16 * VTB_PITCH);
      O[nt]      = __builtin_amdgcn_mfma_f32_16x16x32_f16(pa0, bv, O[nt], 0, 0, 0);
      O[16 + nt] = __builtin_amdgcn_mfma_f32_16x16x32_f16(pa1, bv, O[16 + nt], 0, 0, 0);
    }

    __syncthreads();   // B2: kbuf/vtb/pb(t) consumed; DMA(t+1) drained (vmcnt 0)
    if (t < NTILES - 1) {
      convert_tile(kpe_nxt);
      __syncthreads();   // B3: kbuf/vtb(t+1) valid
    }
  }

  // ---- epilogue ----
  if (lane < 16) {
    l_lds[w * 16 + lane] = lr;
    const int sbase = blockIdx.x * H_SZ + w * 16 + lane;
    wsM[sbase] = mr;
    wsL[sbase] = lr;
  }
  __syncthreads();
  f32x4 lv0 = *(const f32x4*)(l_lds + hg * 32 + quad * 4);
  f32x4 lv1 = *(const f32x4*)(l_lds + hg * 32 + 16 + quad * 4);
  f32x4 iv0, iv1;
#pragma unroll
  for (int i = 0; i < 4; ++i) { iv0[i] = 1.0f / lv0[i]; iv1[i] = 1.0f / lv1[i]; }

  _Float16* ob = (_Float16*)smem;   // [128][520]
  const int rb = hg * 32 + quad * 4;
  const int cb = dh * 256 + l15;
#pragma unroll
  for (int nt = 0; nt < 16; ++nt) {
#pragma unroll
    for (int i = 0; i < 4; ++i) {
      ob[(rb + i) * OB_PITCH + cb + nt * 16]      = (_Float16)(O[nt][i] * iv0[i]);
      ob[(rb + 16 + i) * OB_PITCH + cb + nt * 16] = (_Float16)(O[16 + nt][i] * iv1[i]);
    }
  }
  __syncthreads();
  const size_t obase = (size_t)blockIdx.x * H_SZ * D_SZ;
#pragma unroll
  for (int j = 0; j < 16; ++j) {
    int idx = tid + 512 * j;        // 0..8191
    int h   = idx >> 6;
    int d8  = (idx & 63) * 8;
    f16x8 v = *(const f16x8*)(ob + h * OB_PITCH + d8);
    *(f16x8*)(wsO + obase + h * D_SZ + d8) = v;
  }
}

__global__ void mla_combine(const _Float16* __restrict__ wsO, const float* __restrict__ wsM,
                            const float* __restrict__ wsL, float* __restrict__ out) {
  int tidg = blockIdx.x * 256 + threadIdx.x;   // 0..524287
  int row  = tidg >> 6;                        // b*128+h
  int d8   = (tidg & 63) * 8;
  int b    = row >> 7;
  int h    = row & 127;

  float mv[4], lv[4];
#pragma unroll
  for (int c = 0; c < 4; ++c) {
    mv[c] = wsM[(b * 4 + c) * 128 + h];
    lv[c] = wsL[(b * 4 + c) * 128 + h];
  }
  float M = fmaxf(fmaxf(mv[0], mv[1]), fmaxf(mv[2], mv[3]));
  float wv[4], wsum = 0.f;
#pragma unroll
  for (int c = 0; c < 4; ++c) {
    wv[c] = lv[c] * exp2f((mv[c] - M) * CSCALE);
    wsum += wv[c];
  }
  float o[8] = {0.f, 0.f, 0.f, 0.f, 0.f, 0.f, 0.f, 0.f};
#pragma unroll
  for (int c = 0; c < 4; ++c) {
    f16x8 v = *(const f16x8*)(wsO + (size_t)((b * 4 + c) * 128 + h) * 512 + d8);
#pragma unroll
    for (int j = 0; j < 8; ++j) o[j] += wv[c] * (float)v[j];
  }
  float r = 1.0f / wsum;
  f32x4 r0 = (f32x4){o[0] * r, o[1] * r, o[2] * r, o[3] * r};
  f32x4 r1 = (f32x4){o[4] * r, o[5] * r, o[6] * r, o[7] * r};
  *(f32x4*)(out + (size_t)row * 512 + d8) = r0;
  *(f32x4*)(out + (size_t)row * 512 + d8 + 4) = r1;
}

extern "C" void kernel_launch(void* const* d_in, const int* in_sizes, int n_in,
                              void* d_out, int out_size, void* d_ws, size_t ws_size,
                              hipStream_t stream) {
  if (ws_size < WS_NEEDED) return;   // fail loudly (output left poisoned)
  const float* Q   = (const float*)d_in[0];
  const float* Qpe = (const float*)d_in[1];
  const float* KV  = (const float*)d_in[2];
  const float* Kpe = (const float*)d_in[3];
  _Float16* wsO = (_Float16*)d_ws;
  float* wsM = (float*)((char*)d_ws + WSM_OFF);
  float* wsL = (float*)((char*)d_ws + WSL_OFF);

  mla_partial<<<dim3(B_SZ * NCHUNK), dim3(512), 0, stream>>>(Q, Qpe, KV, Kpe, wsO, wsM, wsL);
  mla_combine<<<dim3(2048), dim3(256), 0, stream>>>(wsO, wsM, wsL, (float*)d_out);
}